// Round 6
// baseline (53.362 us; speedup 1.0000x reference)
//
#include <hip/hip_runtime.h>
#include <hip/hip_bf16.h>

// Problem constants (B,N,H,O) = (2,512,128,32)
#define NN 512
#define HH 128
#define OO 32

// 2*log2(e): tanh(x) = 1 - 2/(2^(KL*xa)*2^(KL*xb)+1) with x = xa+xb
#define KL 2.8853900817779268f

__device__ __forceinline__ float vexp2(float x) {
    float r; asm("v_exp_f32 %0, %1" : "=v"(r) : "v"(x)); return r;
}
__device__ __forceinline__ float vrcp(float x) {
    float r; asm("v_rcp_f32 %0, %1" : "=v"(r) : "v"(x)); return r;
}
__device__ __forceinline__ float tanh_fast(float x) {
    float e = vexp2(KL * x);
    return 1.0f - 2.0f * vrcp(e + 1.0f);
}
__device__ __forceinline__ float waveRedMax(float v) {
#pragma unroll
    for (int off = 32; off > 0; off >>= 1) v = fmaxf(v, __shfl_xor(v, off, 64));
    return v;
}
__device__ __forceinline__ float waveRedSum(float v) {
#pragma unroll
    for (int off = 32; off > 0; off >>= 1) v += __shfl_xor(v, off, 64);
    return v;
}
__device__ __forceinline__ float red8(float v) {   // sum within 8-lane group
    v += __shfl_xor(v, 1, 64); v += __shfl_xor(v, 2, 64); v += __shfl_xor(v, 4, 64);
    return v;
}
__device__ __forceinline__ float dot16(const float4* w, const float* x) {
    float a = 0;
#pragma unroll
    for (int i = 0; i < 4; i++) {
        float4 xv = *(const float4*)(x + i * 4);
        a = fmaf(xv.x, w[i].x, a); a = fmaf(xv.y, w[i].y, a);
        a = fmaf(xv.z, w[i].z, a); a = fmaf(xv.w, w[i].w, a);
    }
    return a;
}

// ---------------------------------------------------------------------------
// Single kernel, 256 blocks x 1024 threads, 1 block/CU (all blocks resident).
//   A: load this block's z/s_t rows
//   P: prep GEMVs (orig-layout weights, 8-lane split): q,Ezi -> LDS;
//      Ezj,kT -> global (this block's 4 rows / 4 columns)
//   [device arrival counter per batch: release-fence + atomicAdd; spin]
//   B: scores, kT read once (h-split)
//   C: masked softmax
//   D: acc += attn * rcp(fma(Ezi,Ezj,1)); U = 1-2*acc
//   E: tail GEMVs from original W2/W3/W4 (8-lane split + shuffle reduce)
// ---------------------------------------------------------------------------
__global__ __launch_bounds__(1024, 4) void ode_one(
    const float* __restrict__ z, const float* __restrict__ s_t,
    const float* __restrict__ W1, const float* __restrict__ b1,
    const float* __restrict__ W2, const float* __restrict__ b2,
    const float* __restrict__ Wq, const float* __restrict__ bq,
    const float* __restrict__ Wk, const float* __restrict__ bk,
    const float* __restrict__ W3, const float* __restrict__ b3,
    const float* __restrict__ W4, const float* __restrict__ b4,
    float* __restrict__ out,
    float* __restrict__ kTG, float* __restrict__ EzjG, int* __restrict__ cnt) {

    __shared__ float zrow[4][HH];        // 2KB
    __shared__ float srow[4][OO];        // 0.5KB
    __shared__ float q4T[HH][4];         // 2KB  q packed [h][r]
    __shared__ float c4T[HH][4];         // 2KB  Ezi packed [h][r]
    __shared__ float attnT[NN][4];       // 8KB  attn packed [j][r]
    __shared__ float buf[8192];          // 32KB: scp[2][4][NN] in B/C; part[16][4][HH] in D
    __shared__ float UL[4][HH];          // 2KB
    __shared__ float aggL[4][HH];        // 2KB
    __shared__ float h1L[4][HH];         // 2KB
    __shared__ float redA[16], redB[16];

    float (*scp)[4][NN] = (float (*)[4][NN])buf;
    float (*part)[4][HH] = (float (*)[4][HH])buf;

    int t = threadIdx.x;
    int bid = blockIdx.x;
    int b = bid >> 7;
    int i0 = (bid & 127) * 4;
    int r0 = bid * 4;                    // global row base = b*512 + i0

    // ---- A: load this block's z/s_t rows ----
    if (t < 4 * HH) zrow[t >> 7][t & 127] = z[(size_t)r0 * HH + t];
    else if (t < 4 * HH + 4 * OO) {
        int u = t - 4 * HH;
        srow[u >> 5][u & 31] = s_t[(size_t)r0 * OO + u];
    }
    __syncthreads();

    // ---- P: prep GEMVs (8 lanes per output row h) ----
    {
        int kq = t & 7, h = t >> 3;
        float vbq = bq[h], vb1 = b1[h], vbk = bk[h];
        float4 w[4];
        float a0, a1, a2, a3;
        // Wq -> q4T (LDS)
        {
            const float4* Wp = (const float4*)(Wq + (size_t)h * HH) + kq * 4;
#pragma unroll
            for (int i = 0; i < 4; i++) w[i] = Wp[i];
            a0 = red8(dot16(w, &zrow[0][kq * 16]));
            a1 = red8(dot16(w, &zrow[1][kq * 16]));
            a2 = red8(dot16(w, &zrow[2][kq * 16]));
            a3 = red8(dot16(w, &zrow[3][kq * 16]));
            if (kq == 0) {
                q4T[h][0] = a0 + vbq; q4T[h][1] = a1 + vbq;
                q4T[h][2] = a2 + vbq; q4T[h][3] = a3 + vbq;
            }
        }
        // W1i -> c4T (LDS)
        {
            const float4* Wp = (const float4*)(W1 + (size_t)h * 2 * HH) + kq * 4;
#pragma unroll
            for (int i = 0; i < 4; i++) w[i] = Wp[i];
            a0 = red8(dot16(w, &zrow[0][kq * 16]));
            a1 = red8(dot16(w, &zrow[1][kq * 16]));
            a2 = red8(dot16(w, &zrow[2][kq * 16]));
            a3 = red8(dot16(w, &zrow[3][kq * 16]));
            if (kq == 0) {
                c4T[h][0] = vexp2(KL * (a0 + vb1)); c4T[h][1] = vexp2(KL * (a1 + vb1));
                c4T[h][2] = vexp2(KL * (a2 + vb1)); c4T[h][3] = vexp2(KL * (a3 + vb1));
            }
        }
        // W1j -> EzjG (global)
        {
            const float4* Wp = (const float4*)(W1 + (size_t)h * 2 * HH + HH) + kq * 4;
#pragma unroll
            for (int i = 0; i < 4; i++) w[i] = Wp[i];
            a0 = red8(dot16(w, &zrow[0][kq * 16]));
            a1 = red8(dot16(w, &zrow[1][kq * 16]));
            a2 = red8(dot16(w, &zrow[2][kq * 16]));
            a3 = red8(dot16(w, &zrow[3][kq * 16]));
            if (kq == 0) {
                EzjG[(size_t)(r0 + 0) * HH + h] = vexp2(KL * a0);
                EzjG[(size_t)(r0 + 1) * HH + h] = vexp2(KL * a1);
                EzjG[(size_t)(r0 + 2) * HH + h] = vexp2(KL * a2);
                EzjG[(size_t)(r0 + 3) * HH + h] = vexp2(KL * a3);
            }
        }
        // Wk -> kTG (global, transposed; 4 consecutive j = float4)
        {
            float4 wk = ((const float4*)(Wk + (size_t)h * OO))[kq];
            float4 s0 = *(const float4*)&srow[0][kq * 4];
            float4 s1 = *(const float4*)&srow[1][kq * 4];
            float4 s2 = *(const float4*)&srow[2][kq * 4];
            float4 s3 = *(const float4*)&srow[3][kq * 4];
            a0 = red8(s0.x * wk.x + s0.y * wk.y + s0.z * wk.z + s0.w * wk.w);
            a1 = red8(s1.x * wk.x + s1.y * wk.y + s1.z * wk.z + s1.w * wk.w);
            a2 = red8(s2.x * wk.x + s2.y * wk.y + s2.z * wk.z + s2.w * wk.w);
            a3 = red8(s3.x * wk.x + s3.y * wk.y + s3.z * wk.z + s3.w * wk.w);
            if (kq == 0) {
                float4 kv = make_float4(a0 + vbk, a1 + vbk, a2 + vbk, a3 + vbk);
                *(float4*)(kTG + ((size_t)b * HH + h) * NN + i0) = kv;
            }
        }
    }
    __syncthreads();   // all global stores drained (vmcnt(0) before barrier)

    // ---- device arrival counter: this batch's 128 producer blocks ----
    if (t == 0) {
        __threadfence();                         // release kT/Ezj to agent scope
        atomicAdd(&cnt[b], 1);
        while (__hip_atomic_load(&cnt[b], __ATOMIC_RELAXED, __HIP_MEMORY_SCOPE_AGENT) < 128) {
            __builtin_amdgcn_s_sleep(2);
        }
        __threadfence();                         // acquire
    }
    __syncthreads();

    // ---- B: scores, h-split ----
    {
        int j = t & 511, hs = t >> 9, h0 = hs * 64;
        const float* kb = kTG + ((size_t)b * HH + h0) * NN + j;
        float s0 = 0, s1 = 0, s2 = 0, s3 = 0;
#pragma unroll 8
        for (int hh = 0; hh < 64; hh++) {
            float kv = kb[(size_t)hh * NN];
            float4 qv = *(const float4*)q4T[h0 + hh];   // broadcast
            s0 = fmaf(qv.x, kv, s0); s1 = fmaf(qv.y, kv, s1);
            s2 = fmaf(qv.z, kv, s2); s3 = fmaf(qv.w, kv, s3);
        }
        scp[hs][0][j] = s0; scp[hs][1][j] = s1;
        scp[hs][2][j] = s2; scp[hs][3][j] = s3;
    }
    __syncthreads();

    // ---- C: masked softmax (2 rows per thread-half) ----
    {
        int rp = t >> 9, j = t & 511;
        int lr0 = rp * 2, lr1 = lr0 + 1;
        const float sc = 0.08838834764831845f;  // 1/sqrt(128)
        float s0 = (scp[0][lr0][j] + scp[1][lr0][j]) * sc;
        float s1 = (scp[0][lr1][j] + scp[1][lr1][j]) * sc;
        if (j == i0 + lr0) s0 = -1e30f;
        if (j == i0 + lr1) s1 = -1e30f;
        int lane = t & 63, w = t >> 6, wb = rp * 8;
        float m0 = waveRedMax(s0), m1 = waveRedMax(s1);
        if (lane == 0) { redA[w] = m0; redB[w] = m1; }
        __syncthreads();
        float mm0 = redA[wb], mm1 = redB[wb];
#pragma unroll
        for (int k = 1; k < 8; k++) { mm0 = fmaxf(mm0, redA[wb + k]); mm1 = fmaxf(mm1, redB[wb + k]); }
        float e0 = __expf(s0 - mm0), e1 = __expf(s1 - mm1);
        float p0 = waveRedSum(e0), p1 = waveRedSum(e1);
        __syncthreads();
        if (lane == 0) { redA[w] = p0; redB[w] = p1; }
        __syncthreads();
        float S0 = redA[wb], S1 = redB[wb];
#pragma unroll
        for (int k = 1; k < 8; k++) { S0 += redA[wb + k]; S1 += redB[wb + k]; }
        attnT[j][lr0] = e0 * __fdividef(1.0f, S0);
        attnT[j][lr1] = e1 * __fdividef(1.0f, S1);
    }
    __syncthreads();

    // ---- D: rcp core. thread = (j-slice, h-pair); 8 independent chains ----
    {
        int lane6 = t & 63, qs = t >> 6;     // 16 slices x 32 j
        int hp = lane6 * 2;
        float4 cA = *(const float4*)c4T[hp];       // Ezi rows 0..3 at h=hp
        float4 cB = *(const float4*)c4T[hp + 1];   // at h=hp+1
        const float2* zb2 = (const float2*)(EzjG + (size_t)b * NN * HH) + lane6;
        float a0A = 0, a1A = 0, a2A = 0, a3A = 0;
        float a0B = 0, a1B = 0, a2B = 0, a3B = 0;
        int jb = qs * 32;
#pragma unroll 8
        for (int jj = 0; jj < 32; jj++) {
            int j = jb + jj;
            float2 E = zb2[(size_t)j * 64];
            float4 w = *(const float4*)attnT[j];   // broadcast
            a0A = fmaf(w.x, vrcp(fmaf(cA.x, E.x, 1.0f)), a0A);
            a1A = fmaf(w.y, vrcp(fmaf(cA.y, E.x, 1.0f)), a1A);
            a2A = fmaf(w.z, vrcp(fmaf(cA.z, E.x, 1.0f)), a2A);
            a3A = fmaf(w.w, vrcp(fmaf(cA.w, E.x, 1.0f)), a3A);
            a0B = fmaf(w.x, vrcp(fmaf(cB.x, E.y, 1.0f)), a0B);
            a1B = fmaf(w.y, vrcp(fmaf(cB.y, E.y, 1.0f)), a1B);
            a2B = fmaf(w.z, vrcp(fmaf(cB.z, E.y, 1.0f)), a2B);
            a3B = fmaf(w.w, vrcp(fmaf(cB.w, E.y, 1.0f)), a3B);
        }
        __syncthreads();   // scp reads done (C) before part overwrite
        *(float2*)&part[qs][0][hp] = make_float2(a0A, a0B);
        *(float2*)&part[qs][1][hp] = make_float2(a1A, a1B);
        *(float2*)&part[qs][2][hp] = make_float2(a2A, a2B);
        *(float2*)&part[qs][3][hp] = make_float2(a3A, a3B);
    }
    __syncthreads();
    if (t < 512) {
        int r = t >> 7, h = t & 127;
        float s = 0;
#pragma unroll
        for (int q = 0; q < 16; q++) s += part[q][r][h];
        UL[r][h] = fmaf(-2.0f, s, 1.0f);   // U = 1 - 2*sum (softmax sums to 1)
    }
    __syncthreads();

    // ---- E: tail GEMVs, original weight layout, 8-lane split ----
    {
        int kq = t & 7, h = t >> 3;
        float vb2 = b2[h], vb3 = b3[h], vb4 = b4[h];
        float4 w[4];
        // agg = U@W2.T + b2
        {
            const float4* Wp = (const float4*)(W2 + (size_t)h * HH) + kq * 4;
#pragma unroll
            for (int i = 0; i < 4; i++) w[i] = Wp[i];
            float a0 = red8(dot16(w, &UL[0][kq * 16]));
            float a1 = red8(dot16(w, &UL[1][kq * 16]));
            float a2 = red8(dot16(w, &UL[2][kq * 16]));
            float a3 = red8(dot16(w, &UL[3][kq * 16]));
            if (kq == 0) {
                aggL[0][h] = a0 + vb2; aggL[1][h] = a1 + vb2;
                aggL[2][h] = a2 + vb2; aggL[3][h] = a3 + vb2;
            }
        }
        __syncthreads();
        // h1 = tanh(agg@W3.T + b3)
        {
            const float4* Wp = (const float4*)(W3 + (size_t)h * HH) + kq * 4;
#pragma unroll
            for (int i = 0; i < 4; i++) w[i] = Wp[i];
            float a0 = red8(dot16(w, &aggL[0][kq * 16]));
            float a1 = red8(dot16(w, &aggL[1][kq * 16]));
            float a2 = red8(dot16(w, &aggL[2][kq * 16]));
            float a3 = red8(dot16(w, &aggL[3][kq * 16]));
            if (kq == 0) {
                h1L[0][h] = tanh_fast(a0 + vb3); h1L[1][h] = tanh_fast(a1 + vb3);
                h1L[2][h] = tanh_fast(a2 + vb3); h1L[3][h] = tanh_fast(a3 + vb3);
            }
        }
        __syncthreads();
        // out = h1@W4.T + b4
        {
            const float4* Wp = (const float4*)(W4 + (size_t)h * HH) + kq * 4;
#pragma unroll
            for (int i = 0; i < 4; i++) w[i] = Wp[i];
            float a0 = red8(dot16(w, &h1L[0][kq * 16]));
            float a1 = red8(dot16(w, &h1L[1][kq * 16]));
            float a2 = red8(dot16(w, &h1L[2][kq * 16]));
            float a3 = red8(dot16(w, &h1L[3][kq * 16]));
            if (kq == 0) {
                out[(size_t)(r0 + 0) * HH + h] = a0 + vb4;
                out[(size_t)(r0 + 1) * HH + h] = a1 + vb4;
                out[(size_t)(r0 + 2) * HH + h] = a2 + vb4;
                out[(size_t)(r0 + 3) * HH + h] = a3 + vb4;
            }
        }
    }
}

extern "C" void kernel_launch(void* const* d_in, const int* in_sizes, int n_in,
                              void* d_out, int out_size, void* d_ws, size_t ws_size,
                              hipStream_t stream) {
    const float* z   = (const float*)d_in[0];
    const float* s_t = (const float*)d_in[1];
    const float* W1  = (const float*)d_in[2];
    const float* b1  = (const float*)d_in[3];
    const float* W2  = (const float*)d_in[4];
    const float* b2  = (const float*)d_in[5];
    const float* Wq  = (const float*)d_in[6];
    const float* bq  = (const float*)d_in[7];
    const float* Wk  = (const float*)d_in[8];
    const float* bk  = (const float*)d_in[9];
    const float* W3  = (const float*)d_in[10];
    const float* b3  = (const float*)d_in[11];
    const float* W4  = (const float*)d_in[12];
    const float* b4  = (const float*)d_in[13];
    float* out = (float*)d_out;

    float* ws  = (float*)d_ws;
    float* kT  = ws;                 // 131072  [b][h][j]
    float* Ezj = ws + 131072;        // 131072  [gr][h]
    int*   cnt = (int*)(ws + 262144);

    hipMemsetAsync(cnt, 0, 2 * sizeof(int), stream);
    hipLaunchKernelGGL(ode_one, dim3(256), dim3(1024), 0, stream,
                       z, s_t, W1, b1, W2, b2, Wq, bq, Wk, bk, W3, b3, W4, b4,
                       out, kT, Ezj, cnt);
}

// Round 7
// 35.937 us; speedup vs baseline: 1.4849x; 1.4849x over previous
//
#include <hip/hip_runtime.h>
#include <hip/hip_bf16.h>

// Problem constants (B,N,H,O) = (2,512,128,32)
#define NN 512
#define HH 128
#define OO 32

// 2*log2(e): tanh(x) = 1 - 2/(2^(KL*xa)*2^(KL*xb)+1) with x = xa+xb
#define KL 2.8853900817779268f

__device__ __forceinline__ float vexp2(float x) {
    float r; asm("v_exp_f32 %0, %1" : "=v"(r) : "v"(x)); return r;
}
__device__ __forceinline__ float vrcp(float x) {
    float r; asm("v_rcp_f32 %0, %1" : "=v"(r) : "v"(x)); return r;
}
__device__ __forceinline__ float tanh_fast(float x) {
    float e = vexp2(KL * x);
    return 1.0f - 2.0f * vrcp(e + 1.0f);
}
__device__ __forceinline__ float waveRedMax(float v) {
#pragma unroll
    for (int off = 32; off > 0; off >>= 1) v = fmaxf(v, __shfl_xor(v, off, 64));
    return v;
}
__device__ __forceinline__ float waveRedSum(float v) {
#pragma unroll
    for (int off = 32; off > 0; off >>= 1) v += __shfl_xor(v, off, 64);
    return v;
}
__device__ __forceinline__ float red8(float v) {   // sum within 8-lane group
    v += __shfl_xor(v, 1, 64); v += __shfl_xor(v, 2, 64); v += __shfl_xor(v, 4, 64);
    return v;
}
// Rotated 16-dot: weights w[] pre-rotated at load; LDS x read at rotated
// offsets so each kq group hits a distinct bank quad (conflict-free).
__device__ __forceinline__ float dot16r(const float4* w, const float* x, int rot) {
    float a = 0;
#pragma unroll
    for (int ii = 0; ii < 4; ii++) {
        int i = (ii + rot) & 3;
        float4 xv = *(const float4*)(x + i * 4);
        a = fmaf(xv.x, w[ii].x, a); a = fmaf(xv.y, w[ii].y, a);
        a = fmaf(xv.z, w[ii].z, a); a = fmaf(xv.w, w[ii].w, a);
    }
    return a;
}
__device__ __forceinline__ unsigned short f2bf(float x) {   // RNE f32->bf16
    unsigned u = __float_as_uint(x);
    u += 0x7fffu + ((u >> 16) & 1u);
    return (unsigned short)(u >> 16);
}
__device__ __forceinline__ float bf_lo(unsigned u) { return __uint_as_float((u & 0xffffu) << 16); }
__device__ __forceinline__ float bf_hi(unsigned u) { return __uint_as_float(u & 0xffff0000u); }

// ---------------------------------------------------------------------------
// K1: cross-block tensors only. 256 blocks x 1024 thr, 4 rows/block.
//   Ezj[gr][h] = bf16(2^(KL * z@W1j.T))  ;  kT[b][h][j] = s_t@Wk.T + bk.
// ---------------------------------------------------------------------------
__global__ __launch_bounds__(1024, 4) void ezj_kt_kernel(
    const float* __restrict__ z, const float* __restrict__ s_t,
    const float* __restrict__ W1, const float* __restrict__ Wk,
    const float* __restrict__ bk,
    unsigned short* __restrict__ EzjG, float* __restrict__ kTG) {
    __shared__ float zrow[4][HH];
    __shared__ float srow[4][OO];
    int t = threadIdx.x, bid = blockIdx.x;
    int r0 = bid * 4;
    int b = bid >> 7, i0 = (bid & 127) * 4;
    if (t < 4 * HH) zrow[t >> 7][t & 127] = z[(size_t)r0 * HH + t];
    else if (t < 4 * HH + 4 * OO) {
        int u = t - 4 * HH;
        srow[u >> 5][u & 31] = s_t[(size_t)r0 * OO + u];
    }
    __syncthreads();

    int kq = t & 7, h = t >> 3, rot = (kq >> 1) & 3;
    // ---- W1j -> Ezj (bf16) ----
    {
        const float4* Wp = (const float4*)(W1 + (size_t)h * 2 * HH + HH) + kq * 4;
        float4 w[4];
#pragma unroll
        for (int ii = 0; ii < 4; ii++) w[ii] = Wp[(ii + rot) & 3];
        float a0 = red8(dot16r(w, &zrow[0][kq * 16], rot));
        float a1 = red8(dot16r(w, &zrow[1][kq * 16], rot));
        float a2 = red8(dot16r(w, &zrow[2][kq * 16], rot));
        float a3 = red8(dot16r(w, &zrow[3][kq * 16], rot));
        if (kq == 0) {
            EzjG[(size_t)(r0 + 0) * HH + h] = f2bf(vexp2(KL * a0));
            EzjG[(size_t)(r0 + 1) * HH + h] = f2bf(vexp2(KL * a1));
            EzjG[(size_t)(r0 + 2) * HH + h] = f2bf(vexp2(KL * a2));
            EzjG[(size_t)(r0 + 3) * HH + h] = f2bf(vexp2(KL * a3));
        }
    }
    // ---- Wk -> kT (fp32, transposed; 4 consecutive j = float4) ----
    {
        float4 wk = ((const float4*)(Wk + (size_t)h * OO))[kq];
        float4 s0 = *(const float4*)&srow[0][kq * 4];
        float4 s1 = *(const float4*)&srow[1][kq * 4];
        float4 s2 = *(const float4*)&srow[2][kq * 4];
        float4 s3 = *(const float4*)&srow[3][kq * 4];
        float a0 = red8(s0.x * wk.x + s0.y * wk.y + s0.z * wk.z + s0.w * wk.w);
        float a1 = red8(s1.x * wk.x + s1.y * wk.y + s1.z * wk.z + s1.w * wk.w);
        float a2 = red8(s2.x * wk.x + s2.y * wk.y + s2.z * wk.z + s2.w * wk.w);
        float a3 = red8(s3.x * wk.x + s3.y * wk.y + s3.z * wk.z + s3.w * wk.w);
        if (kq == 0) {
            float vbk = bk[h];
            float4 kv = make_float4(a0 + vbk, a1 + vbk, a2 + vbk, a3 + vbk);
            *(float4*)(kTG + ((size_t)b * HH + h) * NN + i0) = kv;
        }
    }
}

// ---------------------------------------------------------------------------
// K2: fused — 256 blocks x 1024 thr, 4 attention rows per block (1/CU).
//   A : load z rows
//   P': local q/Ezi GEMVs (Wq, W1i, rotated reads) -> LDS packed [h][4]
//   B : scores, kT read once (h-split)
//   C : masked softmax
//   D : acc += attn * rcp(fma(Ezi, bf16(Ezj), 1)); U = 1-2*acc
//   E : tail GEMVs, original W2/W3/W4 layout, rotated reads
// ---------------------------------------------------------------------------
__global__ __launch_bounds__(1024, 4) void fused_kernel(
    const float* __restrict__ z,
    const float* __restrict__ Wq, const float* __restrict__ bq,
    const float* __restrict__ W1, const float* __restrict__ b1,
    const float* __restrict__ kTG, const unsigned short* __restrict__ EzjG,
    const float* __restrict__ W2, const float* __restrict__ b2,
    const float* __restrict__ W3, const float* __restrict__ b3,
    const float* __restrict__ W4, const float* __restrict__ b4,
    float* __restrict__ out) {
    __shared__ float zrow[4][HH];        // 2KB
    __shared__ float q4T[HH][4];         // 2KB  q packed [h][r]
    __shared__ float c4T[HH][4];         // 2KB  Ezi packed [h][r]
    __shared__ float attnT[NN][4];       // 8KB  attn packed [j][r]
    __shared__ float buf[8192];          // 32KB: scp[2][4][NN] in B/C; part[16][4][HH] in D
    __shared__ float UL[4][HH];          // 2KB
    __shared__ float aggL[4][HH];        // 2KB
    __shared__ float h1L[4][HH];         // 2KB
    __shared__ float redA[16], redB[16];

    float (*scp)[4][NN] = (float (*)[4][NN])buf;
    float (*part)[4][HH] = (float (*)[4][HH])buf;

    int t = threadIdx.x;
    int bid = blockIdx.x;
    int b = bid >> 7;
    int i0 = (bid & 127) * 4;
    int r0 = bid * 4;                    // global row base = b*512 + i0

    // ---- A ----
    if (t < 4 * HH) zrow[t >> 7][t & 127] = z[(size_t)r0 * HH + t];
    __syncthreads();

    // ---- P': local q/Ezi (8-lane split, rotated) ----
    {
        int kq = t & 7, h = t >> 3, rot = (kq >> 1) & 3;
        float4 w[4];
        // Wq -> q4T
        {
            const float4* Wp = (const float4*)(Wq + (size_t)h * HH) + kq * 4;
#pragma unroll
            for (int ii = 0; ii < 4; ii++) w[ii] = Wp[(ii + rot) & 3];
            float a0 = red8(dot16r(w, &zrow[0][kq * 16], rot));
            float a1 = red8(dot16r(w, &zrow[1][kq * 16], rot));
            float a2 = red8(dot16r(w, &zrow[2][kq * 16], rot));
            float a3 = red8(dot16r(w, &zrow[3][kq * 16], rot));
            if (kq == 0) {
                float vbq = bq[h];
                q4T[h][0] = a0 + vbq; q4T[h][1] = a1 + vbq;
                q4T[h][2] = a2 + vbq; q4T[h][3] = a3 + vbq;
            }
        }
        // W1i -> c4T (Ezi)
        {
            const float4* Wp = (const float4*)(W1 + (size_t)h * 2 * HH) + kq * 4;
#pragma unroll
            for (int ii = 0; ii < 4; ii++) w[ii] = Wp[(ii + rot) & 3];
            float a0 = red8(dot16r(w, &zrow[0][kq * 16], rot));
            float a1 = red8(dot16r(w, &zrow[1][kq * 16], rot));
            float a2 = red8(dot16r(w, &zrow[2][kq * 16], rot));
            float a3 = red8(dot16r(w, &zrow[3][kq * 16], rot));
            if (kq == 0) {
                float vb1 = b1[h];
                c4T[h][0] = vexp2(KL * (a0 + vb1)); c4T[h][1] = vexp2(KL * (a1 + vb1));
                c4T[h][2] = vexp2(KL * (a2 + vb1)); c4T[h][3] = vexp2(KL * (a3 + vb1));
            }
        }
    }
    __syncthreads();

    // ---- B: scores, h-split ----
    {
        int j = t & 511, hs = t >> 9, h0 = hs * 64;
        const float* kb = kTG + ((size_t)b * HH + h0) * NN + j;
        float s0 = 0, s1 = 0, s2 = 0, s3 = 0;
#pragma unroll 8
        for (int hh = 0; hh < 64; hh++) {
            float kv = kb[(size_t)hh * NN];
            float4 qv = *(const float4*)q4T[h0 + hh];   // broadcast
            s0 = fmaf(qv.x, kv, s0); s1 = fmaf(qv.y, kv, s1);
            s2 = fmaf(qv.z, kv, s2); s3 = fmaf(qv.w, kv, s3);
        }
        scp[hs][0][j] = s0; scp[hs][1][j] = s1;
        scp[hs][2][j] = s2; scp[hs][3][j] = s3;
    }
    __syncthreads();

    // ---- C: masked softmax (2 rows per thread-half) ----
    {
        int rp = t >> 9, j = t & 511;
        int lr0 = rp * 2, lr1 = lr0 + 1;
        const float sc = 0.08838834764831845f;  // 1/sqrt(128)
        float s0 = (scp[0][lr0][j] + scp[1][lr0][j]) * sc;
        float s1 = (scp[0][lr1][j] + scp[1][lr1][j]) * sc;
        if (j == i0 + lr0) s0 = -1e30f;
        if (j == i0 + lr1) s1 = -1e30f;
        int lane = t & 63, w = t >> 6, wb = rp * 8;
        float m0 = waveRedMax(s0), m1 = waveRedMax(s1);
        if (lane == 0) { redA[w] = m0; redB[w] = m1; }
        __syncthreads();
        float mm0 = redA[wb], mm1 = redB[wb];
#pragma unroll
        for (int k = 1; k < 8; k++) { mm0 = fmaxf(mm0, redA[wb + k]); mm1 = fmaxf(mm1, redB[wb + k]); }
        float e0 = __expf(s0 - mm0), e1 = __expf(s1 - mm1);
        float p0 = waveRedSum(e0), p1 = waveRedSum(e1);
        __syncthreads();
        if (lane == 0) { redA[w] = p0; redB[w] = p1; }
        __syncthreads();
        float S0 = redA[wb], S1 = redB[wb];
#pragma unroll
        for (int k = 1; k < 8; k++) { S0 += redA[wb + k]; S1 += redB[wb + k]; }
        attnT[j][lr0] = e0 * __fdividef(1.0f, S0);
        attnT[j][lr1] = e1 * __fdividef(1.0f, S1);
    }
    __syncthreads();

    // ---- D: rcp core. thread = (j-slice, h-pair); bf16 Ezj, 8 chains ----
    {
        int lane6 = t & 63, qs = t >> 6;     // 16 slices x 32 j
        int hp = lane6 * 2;
        float4 cA = *(const float4*)c4T[hp];       // Ezi rows 0..3 at h=hp
        float4 cB = *(const float4*)c4T[hp + 1];   // at h=hp+1
        const unsigned* zbU = (const unsigned*)(EzjG + (size_t)b * NN * HH) + lane6;
        float a0A = 0, a1A = 0, a2A = 0, a3A = 0;
        float a0B = 0, a1B = 0, a2B = 0, a3B = 0;
        int jb = qs * 32;
#pragma unroll 8
        for (int jj = 0; jj < 32; jj++) {
            int j = jb + jj;
            unsigned u = zbU[(size_t)j * 64];
            float Ex = bf_lo(u), Ey = bf_hi(u);
            float4 w = *(const float4*)attnT[j];   // broadcast
            a0A = fmaf(w.x, vrcp(fmaf(cA.x, Ex, 1.0f)), a0A);
            a1A = fmaf(w.y, vrcp(fmaf(cA.y, Ex, 1.0f)), a1A);
            a2A = fmaf(w.z, vrcp(fmaf(cA.z, Ex, 1.0f)), a2A);
            a3A = fmaf(w.w, vrcp(fmaf(cA.w, Ex, 1.0f)), a3A);
            a0B = fmaf(w.x, vrcp(fmaf(cB.x, Ey, 1.0f)), a0B);
            a1B = fmaf(w.y, vrcp(fmaf(cB.y, Ey, 1.0f)), a1B);
            a2B = fmaf(w.z, vrcp(fmaf(cB.z, Ey, 1.0f)), a2B);
            a3B = fmaf(w.w, vrcp(fmaf(cB.w, Ey, 1.0f)), a3B);
        }
        __syncthreads();   // scp reads done (C) before part overwrite
        *(float2*)&part[qs][0][hp] = make_float2(a0A, a0B);
        *(float2*)&part[qs][1][hp] = make_float2(a1A, a1B);
        *(float2*)&part[qs][2][hp] = make_float2(a2A, a2B);
        *(float2*)&part[qs][3][hp] = make_float2(a3A, a3B);
    }
    __syncthreads();
    if (t < 512) {
        int r = t >> 7, h = t & 127;
        float s = 0;
#pragma unroll
        for (int q = 0; q < 16; q++) s += part[q][r][h];
        UL[r][h] = fmaf(-2.0f, s, 1.0f);   // U = 1 - 2*sum (softmax sums to 1)
    }
    __syncthreads();

    // ---- E: tail GEMVs, original weight layout, rotated reads ----
    {
        int kq = t & 7, h = t >> 3, rot = (kq >> 1) & 3;
        float4 w[4];
        // agg = U@W2.T + b2
        {
            const float4* Wp = (const float4*)(W2 + (size_t)h * HH) + kq * 4;
#pragma unroll
            for (int ii = 0; ii < 4; ii++) w[ii] = Wp[(ii + rot) & 3];
            float a0 = red8(dot16r(w, &UL[0][kq * 16], rot));
            float a1 = red8(dot16r(w, &UL[1][kq * 16], rot));
            float a2 = red8(dot16r(w, &UL[2][kq * 16], rot));
            float a3 = red8(dot16r(w, &UL[3][kq * 16], rot));
            if (kq == 0) {
                float vb2 = b2[h];
                aggL[0][h] = a0 + vb2; aggL[1][h] = a1 + vb2;
                aggL[2][h] = a2 + vb2; aggL[3][h] = a3 + vb2;
            }
        }
        __syncthreads();
        // h1 = tanh(agg@W3.T + b3)
        {
            const float4* Wp = (const float4*)(W3 + (size_t)h * HH) + kq * 4;
#pragma unroll
            for (int ii = 0; ii < 4; ii++) w[ii] = Wp[(ii + rot) & 3];
            float a0 = red8(dot16r(w, &aggL[0][kq * 16], rot));
            float a1 = red8(dot16r(w, &aggL[1][kq * 16], rot));
            float a2 = red8(dot16r(w, &aggL[2][kq * 16], rot));
            float a3 = red8(dot16r(w, &aggL[3][kq * 16], rot));
            if (kq == 0) {
                float vb3 = b3[h];
                h1L[0][h] = tanh_fast(a0 + vb3); h1L[1][h] = tanh_fast(a1 + vb3);
                h1L[2][h] = tanh_fast(a2 + vb3); h1L[3][h] = tanh_fast(a3 + vb3);
            }
        }
        __syncthreads();
        // out = h1@W4.T + b4
        {
            const float4* Wp = (const float4*)(W4 + (size_t)h * HH) + kq * 4;
#pragma unroll
            for (int ii = 0; ii < 4; ii++) w[ii] = Wp[(ii + rot) & 3];
            float a0 = red8(dot16r(w, &h1L[0][kq * 16], rot));
            float a1 = red8(dot16r(w, &h1L[1][kq * 16], rot));
            float a2 = red8(dot16r(w, &h1L[2][kq * 16], rot));
            float a3 = red8(dot16r(w, &h1L[3][kq * 16], rot));
            if (kq == 0) {
                float vb4 = b4[h];
                out[(size_t)(r0 + 0) * HH + h] = a0 + vb4;
                out[(size_t)(r0 + 1) * HH + h] = a1 + vb4;
                out[(size_t)(r0 + 2) * HH + h] = a2 + vb4;
                out[(size_t)(r0 + 3) * HH + h] = a3 + vb4;
            }
        }
    }
}

extern "C" void kernel_launch(void* const* d_in, const int* in_sizes, int n_in,
                              void* d_out, int out_size, void* d_ws, size_t ws_size,
                              hipStream_t stream) {
    const float* z   = (const float*)d_in[0];
    const float* s_t = (const float*)d_in[1];
    const float* W1  = (const float*)d_in[2];
    const float* b1  = (const float*)d_in[3];
    const float* W2  = (const float*)d_in[4];
    const float* b2  = (const float*)d_in[5];
    const float* Wq  = (const float*)d_in[6];
    const float* bq  = (const float*)d_in[7];
    const float* Wk  = (const float*)d_in[8];
    const float* bk  = (const float*)d_in[9];
    const float* W3  = (const float*)d_in[10];
    const float* b3  = (const float*)d_in[11];
    const float* W4  = (const float*)d_in[12];
    const float* b4  = (const float*)d_in[13];
    float* out = (float*)d_out;

    float* ws = (float*)d_ws;
    float* kT = ws;                                   // 131072 floats [b][h][j]
    unsigned short* Ezj = (unsigned short*)(ws + 131072);  // 131072 bf16 [gr][h]

    hipLaunchKernelGGL(ezj_kt_kernel, dim3(256), dim3(1024), 0, stream,
                       z, s_t, W1, Wk, bk, Ezj, kT);
    hipLaunchKernelGGL(fused_kernel, dim3(256), dim3(1024), 0, stream,
                       z, Wq, bq, W1, b1, kT, Ezj, W2, b2, W3, b3, W4, b4, out);
}

// Round 8
// 35.506 us; speedup vs baseline: 1.5029x; 1.0121x over previous
//
#include <hip/hip_runtime.h>
#include <hip/hip_bf16.h>

// Problem constants (B,N,H,O) = (2,512,128,32)
#define NN 512
#define HH 128
#define OO 32

// 2*log2(e): tanh(x) = 1 - 2/(2^(KL*xa)*2^(KL*xb)+1) with x = xa+xb
#define KL 2.8853900817779268f

__device__ __forceinline__ float vexp2(float x) {
    float r; asm("v_exp_f32 %0, %1" : "=v"(r) : "v"(x)); return r;
}
__device__ __forceinline__ float vrcp(float x) {
    float r; asm("v_rcp_f32 %0, %1" : "=v"(r) : "v"(x)); return r;
}
__device__ __forceinline__ float tanh_fast(float x) {
    float e = vexp2(KL * x);
    return 1.0f - 2.0f * vrcp(e + 1.0f);
}
__device__ __forceinline__ float waveRedMax(float v) {
#pragma unroll
    for (int off = 32; off > 0; off >>= 1) v = fmaxf(v, __shfl_xor(v, off, 64));
    return v;
}
__device__ __forceinline__ float waveRedSum(float v) {
#pragma unroll
    for (int off = 32; off > 0; off >>= 1) v += __shfl_xor(v, off, 64);
    return v;
}
__device__ __forceinline__ float red8(float v) {   // sum within 8-lane group
    v += __shfl_xor(v, 1, 64); v += __shfl_xor(v, 2, 64); v += __shfl_xor(v, 4, 64);
    return v;
}
// Rotated 16-dot: weights pre-rotated at load; LDS x read at rotated offsets
// so each kq group hits a distinct bank quad (conflict-free).
__device__ __forceinline__ float dot16r(const float4* w, const float* x, int rot) {
    float a = 0;
#pragma unroll
    for (int ii = 0; ii < 4; ii++) {
        int i = (ii + rot) & 3;
        float4 xv = *(const float4*)(x + i * 4);
        a = fmaf(xv.x, w[ii].x, a); a = fmaf(xv.y, w[ii].y, a);
        a = fmaf(xv.z, w[ii].z, a); a = fmaf(xv.w, w[ii].w, a);
    }
    return a;
}
__device__ __forceinline__ unsigned short f2bf(float x) {   // RNE f32->bf16
    unsigned u = __float_as_uint(x);
    u += 0x7fffu + ((u >> 16) & 1u);
    return (unsigned short)(u >> 16);
}
__device__ __forceinline__ float bf_lo(unsigned u) { return __uint_as_float((u & 0xffffu) << 16); }
__device__ __forceinline__ float bf_hi(unsigned u) { return __uint_as_float(u & 0xffff0000u); }

// ---------------------------------------------------------------------------
// K1: ALL producer work. 256 blocks x 1024 thr, 4 rows/block.
//   qP/cP packed [bid][h][4] (q and Ezi) ; Ezj[gr][h] bf16 ; kT[b][h][j] f32.
// Early-issued weight loads; rotated LDS reads (bank-conflict-free).
// ---------------------------------------------------------------------------
__global__ __launch_bounds__(1024, 4) void prep_kernel(
    const float* __restrict__ z, const float* __restrict__ s_t,
    const float* __restrict__ W1, const float* __restrict__ b1,
    const float* __restrict__ Wq, const float* __restrict__ bq,
    const float* __restrict__ Wk, const float* __restrict__ bk,
    float* __restrict__ qP, float* __restrict__ cP,
    unsigned short* __restrict__ EzjG, float* __restrict__ kTG) {
    __shared__ float zrow[4][HH];
    __shared__ float srow[4][OO];
    int t = threadIdx.x, bid = blockIdx.x;
    int r0 = bid * 4, b = bid >> 7, i0 = (bid & 127) * 4;
    int kq = t & 7, h = t >> 3, rot = (kq >> 1) & 3;

    // ---- early-issue all weight/bias loads (independent of LDS staging) ----
    const float4* WqP = (const float4*)(Wq + (size_t)h * HH) + kq * 4;
    const float4* WiP = (const float4*)(W1 + (size_t)h * 2 * HH) + kq * 4;
    const float4* WjP = (const float4*)(W1 + (size_t)h * 2 * HH + HH) + kq * 4;
    float4 wq[4], wi[4], wj[4];
#pragma unroll
    for (int ii = 0; ii < 4; ii++) {
        wq[ii] = WqP[(ii + rot) & 3];
        wi[ii] = WiP[(ii + rot) & 3];
        wj[ii] = WjP[(ii + rot) & 3];
    }
    float4 wk = ((const float4*)(Wk + (size_t)h * OO))[kq];
    float vbq = bq[h], vb1 = b1[h], vbk = bk[h];

    // ---- stage z/s_t rows ----
    if (t < 4 * HH) zrow[t >> 7][t & 127] = z[(size_t)r0 * HH + t];
    else if (t < 4 * HH + 4 * OO) {
        int u = t - 4 * HH;
        srow[u >> 5][u & 31] = s_t[(size_t)r0 * OO + u];
    }
    __syncthreads();   // drains weight loads too

    // ---- q -> qP packed ----
    {
        float a0 = red8(dot16r(wq, &zrow[0][kq * 16], rot));
        float a1 = red8(dot16r(wq, &zrow[1][kq * 16], rot));
        float a2 = red8(dot16r(wq, &zrow[2][kq * 16], rot));
        float a3 = red8(dot16r(wq, &zrow[3][kq * 16], rot));
        if (kq == 0) {
            float* qp = qP + (size_t)bid * 512 + h * 4;
            qp[0] = a0 + vbq; qp[1] = a1 + vbq; qp[2] = a2 + vbq; qp[3] = a3 + vbq;
        }
    }
    // ---- Ezi -> cP packed ----
    {
        float a0 = red8(dot16r(wi, &zrow[0][kq * 16], rot));
        float a1 = red8(dot16r(wi, &zrow[1][kq * 16], rot));
        float a2 = red8(dot16r(wi, &zrow[2][kq * 16], rot));
        float a3 = red8(dot16r(wi, &zrow[3][kq * 16], rot));
        if (kq == 0) {
            float* cp = cP + (size_t)bid * 512 + h * 4;
            cp[0] = vexp2(KL * (a0 + vb1)); cp[1] = vexp2(KL * (a1 + vb1));
            cp[2] = vexp2(KL * (a2 + vb1)); cp[3] = vexp2(KL * (a3 + vb1));
        }
    }
    // ---- Ezj -> bf16 ----
    {
        float a0 = red8(dot16r(wj, &zrow[0][kq * 16], rot));
        float a1 = red8(dot16r(wj, &zrow[1][kq * 16], rot));
        float a2 = red8(dot16r(wj, &zrow[2][kq * 16], rot));
        float a3 = red8(dot16r(wj, &zrow[3][kq * 16], rot));
        if (kq == 0) {
            EzjG[(size_t)(r0 + 0) * HH + h] = f2bf(vexp2(KL * a0));
            EzjG[(size_t)(r0 + 1) * HH + h] = f2bf(vexp2(KL * a1));
            EzjG[(size_t)(r0 + 2) * HH + h] = f2bf(vexp2(KL * a2));
            EzjG[(size_t)(r0 + 3) * HH + h] = f2bf(vexp2(KL * a3));
        }
    }
    // ---- k -> kT (transposed; 4 consecutive j per float4) ----
    {
        float4 s0 = *(const float4*)&srow[0][kq * 4];
        float4 s1 = *(const float4*)&srow[1][kq * 4];
        float4 s2 = *(const float4*)&srow[2][kq * 4];
        float4 s3 = *(const float4*)&srow[3][kq * 4];
        float a0 = red8(s0.x * wk.x + s0.y * wk.y + s0.z * wk.z + s0.w * wk.w);
        float a1 = red8(s1.x * wk.x + s1.y * wk.y + s1.z * wk.z + s1.w * wk.w);
        float a2 = red8(s2.x * wk.x + s2.y * wk.y + s2.z * wk.z + s2.w * wk.w);
        float a3 = red8(s3.x * wk.x + s3.y * wk.y + s3.z * wk.z + s3.w * wk.w);
        if (kq == 0) {
            float4 kv = make_float4(a0 + vbk, a1 + vbk, a2 + vbk, a3 + vbk);
            *(float4*)(kTG + ((size_t)b * HH + h) * NN + i0) = kv;
        }
    }
}

// ---------------------------------------------------------------------------
// K2: pure consumer. 256 blocks x 1024 thr, 4 rows/block (1/CU).
// Issue-early/consume-late everywhere:
//   A-issue (q/c staging) + B-chunk1 loads -> barrier (drain hides latency)
//   B-compute (reg kv) ; D-issue (32 Ezj uints) -> barrier
//   C softmax (hides D loads) ; D-compute ; E-issue (W2/W3/W4) -> barrier
//   UL reduce ; E stages (weights already in regs)
// ---------------------------------------------------------------------------
__global__ __launch_bounds__(1024, 4) void fused_kernel(
    const float* __restrict__ qP, const float* __restrict__ cP,
    const float* __restrict__ kTG, const unsigned short* __restrict__ EzjG,
    const float* __restrict__ W2, const float* __restrict__ b2,
    const float* __restrict__ W3, const float* __restrict__ b3,
    const float* __restrict__ W4, const float* __restrict__ b4,
    float* __restrict__ out) {
    __shared__ float q4T[HH][4];         // 2KB
    __shared__ float c4T[HH][4];         // 2KB
    __shared__ float attnT[NN][4];       // 8KB
    __shared__ float buf[8192];          // 32KB: scp in B/C, part in D
    __shared__ float UL[4][HH];          // 2KB
    __shared__ float aggL[4][HH];        // 2KB
    __shared__ float h1L[4][HH];         // 2KB
    __shared__ float redA[16], redB[16], redC[16], redD[16];

    float (*scp)[4][NN] = (float (*)[4][NN])buf;
    float (*part)[4][HH] = (float (*)[4][HH])buf;

    int t = threadIdx.x, bid = blockIdx.x;
    int b = bid >> 7, i0 = (bid & 127) * 4, r0 = bid * 4;

    // ---- A-issue: stage q/c packed (coalesced) ----
    if (t < 512) ((float*)q4T)[t] = qP[(size_t)bid * 512 + t];
    else         ((float*)c4T)[t - 512] = cP[(size_t)bid * 512 + (t - 512)];

    // ---- B-issue chunk 1 (independent of LDS) ----
    int j = t & 511, hs = t >> 9, h0 = hs * 64;
    const float* kb = kTG + ((size_t)b * HH + h0) * NN + j;
    float kv[32];
#pragma unroll
    for (int hh = 0; hh < 32; hh++) kv[hh] = kb[(size_t)hh * NN];
    __syncthreads();   // drain staging + chunk1

    // ---- B-compute ----
    float s0 = 0, s1 = 0, s2 = 0, s3 = 0;
#pragma unroll
    for (int hh = 0; hh < 32; hh++) {
        float4 qv = *(const float4*)q4T[h0 + hh];   // broadcast
        s0 = fmaf(qv.x, kv[hh], s0); s1 = fmaf(qv.y, kv[hh], s1);
        s2 = fmaf(qv.z, kv[hh], s2); s3 = fmaf(qv.w, kv[hh], s3);
    }
#pragma unroll
    for (int hh = 0; hh < 32; hh++) kv[hh] = kb[(size_t)(32 + hh) * NN];
#pragma unroll
    for (int hh = 0; hh < 32; hh++) {
        float4 qv = *(const float4*)q4T[h0 + 32 + hh];
        s0 = fmaf(qv.x, kv[hh], s0); s1 = fmaf(qv.y, kv[hh], s1);
        s2 = fmaf(qv.z, kv[hh], s2); s3 = fmaf(qv.w, kv[hh], s3);
    }
    scp[hs][0][j] = s0; scp[hs][1][j] = s1;
    scp[hs][2][j] = s2; scp[hs][3][j] = s3;

    // ---- D-issue: 32 Ezj uints (latency hidden under C) ----
    int lane6 = t & 63, qs = t >> 6, hp = lane6 * 2, jb = qs * 32;
    const unsigned* zbU = (const unsigned*)EzjG + (size_t)b * NN * (HH / 2) + lane6;
    unsigned uv[32];
#pragma unroll
    for (int jj = 0; jj < 32; jj++) uv[jj] = zbU[(size_t)(jb + jj) * (HH / 2)];
    __syncthreads();   // scp visible

    // ---- C: masked softmax (2 rows per thread-half; 2 barriers) ----
    {
        int rp = t >> 9;
        int lr0 = rp * 2, lr1 = lr0 + 1;
        const float sc = 0.08838834764831845f;  // 1/sqrt(128)
        float c0 = (scp[0][lr0][j] + scp[1][lr0][j]) * sc;
        float c1 = (scp[0][lr1][j] + scp[1][lr1][j]) * sc;
        if (j == i0 + lr0) c0 = -1e30f;
        if (j == i0 + lr1) c1 = -1e30f;
        int lane = t & 63, w = t >> 6, wb = rp * 8;
        float m0 = waveRedMax(c0), m1 = waveRedMax(c1);
        if (lane == 0) { redA[w] = m0; redB[w] = m1; }
        __syncthreads();
        float mm0 = redA[wb], mm1 = redB[wb];
#pragma unroll
        for (int k = 1; k < 8; k++) { mm0 = fmaxf(mm0, redA[wb + k]); mm1 = fmaxf(mm1, redB[wb + k]); }
        float e0 = __expf(c0 - mm0), e1 = __expf(c1 - mm1);
        float p0 = waveRedSum(e0), p1 = waveRedSum(e1);
        if (lane == 0) { redC[w] = p0; redD[w] = p1; }
        __syncthreads();
        float S0 = redC[wb], S1 = redD[wb];
#pragma unroll
        for (int k = 1; k < 8; k++) { S0 += redC[wb + k]; S1 += redD[wb + k]; }
        attnT[j][lr0] = e0 * __fdividef(1.0f, S0);
        attnT[j][lr1] = e1 * __fdividef(1.0f, S1);
    }
    __syncthreads();

    // ---- D-compute: 8 independent rcp chains per iter, data all in regs ----
    {
        float4 cA = *(const float4*)c4T[hp];       // Ezi rows 0..3 at h=hp
        float4 cB = *(const float4*)c4T[hp + 1];   // at h=hp+1
        float a0A = 0, a1A = 0, a2A = 0, a3A = 0;
        float a0B = 0, a1B = 0, a2B = 0, a3B = 0;
#pragma unroll
        for (int jj = 0; jj < 32; jj++) {
            int jc = jb + jj;
            float Ex = bf_lo(uv[jj]), Ey = bf_hi(uv[jj]);
            float4 w = *(const float4*)attnT[jc];   // broadcast
            a0A = fmaf(w.x, vrcp(fmaf(cA.x, Ex, 1.0f)), a0A);
            a1A = fmaf(w.y, vrcp(fmaf(cA.y, Ex, 1.0f)), a1A);
            a2A = fmaf(w.z, vrcp(fmaf(cA.z, Ex, 1.0f)), a2A);
            a3A = fmaf(w.w, vrcp(fmaf(cA.w, Ex, 1.0f)), a3A);
            a0B = fmaf(w.x, vrcp(fmaf(cB.x, Ey, 1.0f)), a0B);
            a1B = fmaf(w.y, vrcp(fmaf(cB.y, Ey, 1.0f)), a1B);
            a2B = fmaf(w.z, vrcp(fmaf(cB.z, Ey, 1.0f)), a2B);
            a3B = fmaf(w.w, vrcp(fmaf(cB.w, Ey, 1.0f)), a3B);
        }
        *(float2*)&part[qs][0][hp] = make_float2(a0A, a0B);
        *(float2*)&part[qs][1][hp] = make_float2(a1A, a1B);
        *(float2*)&part[qs][2][hp] = make_float2(a2A, a2B);
        *(float2*)&part[qs][3][hp] = make_float2(a3A, a3B);
    }

    // ---- E-issue: all tail weights/biases (drain at next barrier) ----
    int kq = t & 7, h8 = t >> 3, rot = (kq >> 1) & 3;
    const float4* W2p = (const float4*)(W2 + (size_t)h8 * HH) + kq * 4;
    const float4* W3p = (const float4*)(W3 + (size_t)h8 * HH) + kq * 4;
    const float4* W4p = (const float4*)(W4 + (size_t)h8 * HH) + kq * 4;
    float4 w2[4], w3[4], w4[4];
#pragma unroll
    for (int ii = 0; ii < 4; ii++) {
        w2[ii] = W2p[(ii + rot) & 3];
        w3[ii] = W3p[(ii + rot) & 3];
        w4[ii] = W4p[(ii + rot) & 3];
    }
    float vb2 = b2[h8], vb3 = b3[h8], vb4 = b4[h8];
    __syncthreads();   // part visible; weight loads drained

    // ---- UL reduce ----
    if (t < 512) {
        int r = t >> 7, h = t & 127;
        float s = 0;
#pragma unroll
        for (int q = 0; q < 16; q++) s += part[q][r][h];
        UL[r][h] = fmaf(-2.0f, s, 1.0f);   // U = 1 - 2*sum (softmax sums to 1)
    }
    __syncthreads();

    // ---- E: tail GEMVs (weights already in regs, rotated LDS reads) ----
    {
        float a0 = red8(dot16r(w2, &UL[0][kq * 16], rot));
        float a1 = red8(dot16r(w2, &UL[1][kq * 16], rot));
        float a2 = red8(dot16r(w2, &UL[2][kq * 16], rot));
        float a3 = red8(dot16r(w2, &UL[3][kq * 16], rot));
        if (kq == 0) {
            aggL[0][h8] = a0 + vb2; aggL[1][h8] = a1 + vb2;
            aggL[2][h8] = a2 + vb2; aggL[3][h8] = a3 + vb2;
        }
    }
    __syncthreads();
    {
        float a0 = red8(dot16r(w3, &aggL[0][kq * 16], rot));
        float a1 = red8(dot16r(w3, &aggL[1][kq * 16], rot));
        float a2 = red8(dot16r(w3, &aggL[2][kq * 16], rot));
        float a3 = red8(dot16r(w3, &aggL[3][kq * 16], rot));
        if (kq == 0) {
            h1L[0][h8] = tanh_fast(a0 + vb3); h1L[1][h8] = tanh_fast(a1 + vb3);
            h1L[2][h8] = tanh_fast(a2 + vb3); h1L[3][h8] = tanh_fast(a3 + vb3);
        }
    }
    __syncthreads();
    {
        float a0 = red8(dot16r(w4, &h1L[0][kq * 16], rot));
        float a1 = red8(dot16r(w4, &h1L[1][kq * 16], rot));
        float a2 = red8(dot16r(w4, &h1L[2][kq * 16], rot));
        float a3 = red8(dot16r(w4, &h1L[3][kq * 16], rot));
        if (kq == 0) {
            out[(size_t)(r0 + 0) * HH + h8] = a0 + vb4;
            out[(size_t)(r0 + 1) * HH + h8] = a1 + vb4;
            out[(size_t)(r0 + 2) * HH + h8] = a2 + vb4;
            out[(size_t)(r0 + 3) * HH + h8] = a3 + vb4;
        }
    }
}

extern "C" void kernel_launch(void* const* d_in, const int* in_sizes, int n_in,
                              void* d_out, int out_size, void* d_ws, size_t ws_size,
                              hipStream_t stream) {
    const float* z   = (const float*)d_in[0];
    const float* s_t = (const float*)d_in[1];
    const float* W1  = (const float*)d_in[2];
    const float* b1  = (const float*)d_in[3];
    const float* W2  = (const float*)d_in[4];
    const float* b2  = (const float*)d_in[5];
    const float* Wq  = (const float*)d_in[6];
    const float* bq  = (const float*)d_in[7];
    const float* Wk  = (const float*)d_in[8];
    const float* bk  = (const float*)d_in[9];
    const float* W3  = (const float*)d_in[10];
    const float* b3  = (const float*)d_in[11];
    const float* W4  = (const float*)d_in[12];
    const float* b4  = (const float*)d_in[13];
    float* out = (float*)d_out;

    float* ws = (float*)d_ws;
    float* kT = ws;                                        // 131072 f32 [b][h][j]
    float* qP = ws + 131072;                               // 131072 f32 packed
    float* cP = ws + 262144;                               // 131072 f32 packed
    unsigned short* Ezj = (unsigned short*)(ws + 393216);  // 131072 bf16 [gr][h]

    hipLaunchKernelGGL(prep_kernel, dim3(256), dim3(1024), 0, stream,
                       z, s_t, W1, b1, Wq, bq, Wk, bk, qP, cP, Ezj, kT);
    hipLaunchKernelGGL(fused_kernel, dim3(256), dim3(1024), 0, stream,
                       qP, cP, kT, Ezj, W2, b2, W3, b3, W4, b4, out);
}